// Round 9
// baseline (188.026 us; speedup 1.0000x reference)
//
#include <hip/hip_runtime.h>
#include <hip/hip_fp16.h>
#include <math.h>

#define LEAKY 0.01f

__device__ inline float fast_tanh(float x) {
    float e2 = __expf(2.0f * x);
    return 1.0f - 2.0f * __builtin_amdgcn_rcpf(e2 + 1.0f);
}

__device__ inline float2 h2f(uint w) {
    __half2 h = *reinterpret_cast<__half2*>(&w);
    return __half22float2(h);
}

// ---------------------------------------------------------------------------
// Kernel 1 (v3): per-node projections. 64 nodes/block, 4 threads/node.
// z tile (64x64 f32, stride 68 -> 16B-aligned, 2-way max bank conflict) and
// W1 (128x32) staged in LDS; z global traffic = 25.6 MB exactly once.
//   U[n][j] = sum_k z[n][k]*W1[k][j] + b1[j];  V[n][j] = sum_k z[n][k]*W1[64+k][j]
// ---------------------------------------------------------------------------
__global__ __launch_bounds__(256) void node_proj_v3(
    const float* __restrict__ z, const float* __restrict__ W1,
    const float* __restrict__ b1, __half* __restrict__ U, __half* __restrict__ V,
    int N)
{
    __shared__ float w1s[128 * 32];   // 16 KB
    __shared__ float zs[64 * 68];     // 17 KB, row stride 68 floats

    int tid = threadIdx.x;
    // stage W1 (coalesced)
    {
        const float4* src = reinterpret_cast<const float4*>(W1);
        float4* dst = reinterpret_cast<float4*>(w1s);
        #pragma unroll
        for (int i = 0; i < 4; ++i) dst[tid + 256 * i] = src[tid + 256 * i];
    }
    // stage z tile: 64 nodes x 16 float4 = 1024 float4s, 4 per thread
    int n0 = blockIdx.x * 64;
    {
        const float4* zsrc = reinterpret_cast<const float4*>(z);
        #pragma unroll
        for (int r = 0; r < 4; ++r) {
            int i = tid + 256 * r;
            int nl = i >> 4;      // 0..63
            int c  = i & 15;      // float4 chunk
            int n = n0 + nl;
            float4 val = (n < N) ? zsrc[(size_t)n * 16 + c] : make_float4(0, 0, 0, 0);
            *reinterpret_cast<float4*>(&zs[nl * 68 + c * 4]) = val;
        }
    }
    __syncthreads();

    int nl = tid >> 2;
    int g = tid & 3;
    int n = n0 + nl;

    float au[8], av[8];
    {
        float4 b1a = *reinterpret_cast<const float4*>(b1 + g * 8);
        float4 b1b = *reinterpret_cast<const float4*>(b1 + g * 8 + 4);
        au[0] = b1a.x; au[1] = b1a.y; au[2] = b1a.z; au[3] = b1a.w;
        au[4] = b1b.x; au[5] = b1b.y; au[6] = b1b.z; au[7] = b1b.w;
        #pragma unroll
        for (int j = 0; j < 8; ++j) av[j] = 0.0f;
    }

    #pragma unroll 4
    for (int k4 = 0; k4 < 16; ++k4) {
        float4 a = *reinterpret_cast<const float4*>(&zs[nl * 68 + k4 * 4]);
        #pragma unroll
        for (int c = 0; c < 4; ++c) {
            int k = 4 * k4 + c;
            float zk = (c == 0) ? a.x : (c == 1) ? a.y : (c == 2) ? a.z : a.w;
            const float4* wu = reinterpret_cast<const float4*>(&w1s[k * 32 + g * 8]);
            const float4* wv = reinterpret_cast<const float4*>(&w1s[(64 + k) * 32 + g * 8]);
            float4 wu0 = wu[0], wu1 = wu[1];
            float4 wv0 = wv[0], wv1 = wv[1];
            au[0] = fmaf(zk, wu0.x, au[0]);
            au[1] = fmaf(zk, wu0.y, au[1]);
            au[2] = fmaf(zk, wu0.z, au[2]);
            au[3] = fmaf(zk, wu0.w, au[3]);
            au[4] = fmaf(zk, wu1.x, au[4]);
            au[5] = fmaf(zk, wu1.y, au[5]);
            au[6] = fmaf(zk, wu1.z, au[6]);
            au[7] = fmaf(zk, wu1.w, au[7]);
            av[0] = fmaf(zk, wv0.x, av[0]);
            av[1] = fmaf(zk, wv0.y, av[1]);
            av[2] = fmaf(zk, wv0.z, av[2]);
            av[3] = fmaf(zk, wv0.w, av[3]);
            av[4] = fmaf(zk, wv1.x, av[4]);
            av[5] = fmaf(zk, wv1.y, av[5]);
            av[6] = fmaf(zk, wv1.z, av[6]);
            av[7] = fmaf(zk, wv1.w, av[7]);
        }
    }

    if (n < N) {
        uint wu[4], wv[4];
        #pragma unroll
        for (int i = 0; i < 4; ++i) {
            __half2 hu = __floats2half2_rn(au[2 * i], au[2 * i + 1]);
            wu[i] = *reinterpret_cast<uint*>(&hu);
            __half2 hv = __floats2half2_rn(av[2 * i], av[2 * i + 1]);
            wv[i] = *reinterpret_cast<uint*>(&hv);
        }
        *reinterpret_cast<uint4*>(U + (size_t)n * 32 + g * 8) = make_uint4(wu[0], wu[1], wu[2], wu[3]);
        *reinterpret_cast<uint4*>(V + (size_t)n * 32 + g * 8) = make_uint4(wv[0], wv[1], wv[2], wv[3]);
    }
}

// ---------------------------------------------------------------------------
// Kernel 2: quad-cooperative edge decode, 4 edges per quad (unchanged, at the
// random-gather bytes floor: ~293 MB L2-miss traffic @ ~3.7 TB/s).
// ---------------------------------------------------------------------------
__device__ inline float edge_dot(uint4 uq, uint4 vq, float4 w2a, float4 w2b) {
    float acc = 0.0f;
    float2 uu, vv; float h0, h1;
    uu = h2f(uq.x); vv = h2f(vq.x);
    h0 = uu.x + vv.x; h1 = uu.y + vv.y;
    h0 = (h0 >= 0.0f) ? h0 : LEAKY * h0;
    h1 = (h1 >= 0.0f) ? h1 : LEAKY * h1;
    acc = fmaf(h0, w2a.x, acc); acc = fmaf(h1, w2a.y, acc);
    uu = h2f(uq.y); vv = h2f(vq.y);
    h0 = uu.x + vv.x; h1 = uu.y + vv.y;
    h0 = (h0 >= 0.0f) ? h0 : LEAKY * h0;
    h1 = (h1 >= 0.0f) ? h1 : LEAKY * h1;
    acc = fmaf(h0, w2a.z, acc); acc = fmaf(h1, w2a.w, acc);
    uu = h2f(uq.z); vv = h2f(vq.z);
    h0 = uu.x + vv.x; h1 = uu.y + vv.y;
    h0 = (h0 >= 0.0f) ? h0 : LEAKY * h0;
    h1 = (h1 >= 0.0f) ? h1 : LEAKY * h1;
    acc = fmaf(h0, w2b.x, acc); acc = fmaf(h1, w2b.y, acc);
    uu = h2f(uq.w); vv = h2f(vq.w);
    h0 = uu.x + vv.x; h1 = uu.y + vv.y;
    h0 = (h0 >= 0.0f) ? h0 : LEAKY * h0;
    h1 = (h1 >= 0.0f) ? h1 : LEAKY * h1;
    acc = fmaf(h0, w2b.z, acc); acc = fmaf(h1, w2b.w, acc);
    return acc;
}

__global__ __launch_bounds__(256) void edge_decode_q4(
    const int* __restrict__ idx,
    const __half* __restrict__ U, const __half* __restrict__ V,
    const float* __restrict__ W2, const float* __restrict__ b2,
    float* __restrict__ out, int E)
{
    int t = blockIdx.x * blockDim.x + threadIdx.x;
    int p = t & 3;
    int e0 = t & ~3;
    if (e0 >= E) return;
    int eN = E - 1;
    int ea = min(e0, eN), eb = min(e0 + 1, eN), ec = min(e0 + 2, eN), ed = min(e0 + 3, eN);

    int s0 = idx[ea], s1 = idx[eb], s2 = idx[ec], s3 = idx[ed];
    int d0 = idx[E + ea], d1 = idx[E + eb], d2 = idx[E + ec], d3 = idx[E + ed];

    const uint4* Up = reinterpret_cast<const uint4*>(U);
    const uint4* Vp = reinterpret_cast<const uint4*>(V);
    uint4 u0 = Up[(size_t)s0 * 4 + p];
    uint4 u1 = Up[(size_t)s1 * 4 + p];
    uint4 u2 = Up[(size_t)s2 * 4 + p];
    uint4 u3 = Up[(size_t)s3 * 4 + p];
    uint4 v0 = Vp[(size_t)d0 * 4 + p];
    uint4 v1 = Vp[(size_t)d1 * 4 + p];
    uint4 v2 = Vp[(size_t)d2 * 4 + p];
    uint4 v3 = Vp[(size_t)d3 * 4 + p];

    float4 w2a = *reinterpret_cast<const float4*>(W2 + p * 8);
    float4 w2b = *reinterpret_cast<const float4*>(W2 + p * 8 + 4);

    float a0 = edge_dot(u0, v0, w2a, w2b);
    float a1 = edge_dot(u1, v1, w2a, w2b);
    float a2 = edge_dot(u2, v2, w2a, w2b);
    float a3 = edge_dot(u3, v3, w2a, w2b);

    a0 += __shfl_xor(a0, 1); a0 += __shfl_xor(a0, 2);
    a1 += __shfl_xor(a1, 1); a1 += __shfl_xor(a1, 2);
    a2 += __shfl_xor(a2, 1); a2 += __shfl_xor(a2, 2);
    a3 += __shfl_xor(a3, 1); a3 += __shfl_xor(a3, 2);

    float r = (p == 0) ? a0 : (p == 1) ? a1 : (p == 2) ? a2 : a3;
    r = fast_tanh(r + b2[0]);
    int eo = e0 + p;
    if (eo < E) out[eo] = r;
}

// ---------------------------------------------------------------------------
// Fallback if the workspace is too small for U/V.
// ---------------------------------------------------------------------------
__global__ __launch_bounds__(256) void edge_mlp_f32(
    const float* __restrict__ z, const int* __restrict__ idx,
    const float* __restrict__ W1, const float* __restrict__ b1,
    const float* __restrict__ W2, const float* __restrict__ b2,
    float* __restrict__ out, int E)
{
    int e = blockIdx.x * blockDim.x + threadIdx.x;
    if (e >= E) return;
    int s = idx[e];
    int d = idx[E + e];
    const float4* zs = reinterpret_cast<const float4*>(z + (size_t)s * 64);
    const float4* zd = reinterpret_cast<const float4*>(z + (size_t)d * 64);

    float h[32];
    #pragma unroll
    for (int j = 0; j < 32; ++j) h[j] = b1[j];

    #pragma unroll 4
    for (int k4 = 0; k4 < 16; ++k4) {
        float4 a = zs[k4];
        float4 b = zd[k4];
        const float* wa0 = W1 + (4 * k4 + 0) * 32;
        const float* wa1 = W1 + (4 * k4 + 1) * 32;
        const float* wa2 = W1 + (4 * k4 + 2) * 32;
        const float* wa3 = W1 + (4 * k4 + 3) * 32;
        const float* wb0 = W1 + (64 + 4 * k4 + 0) * 32;
        const float* wb1 = W1 + (64 + 4 * k4 + 1) * 32;
        const float* wb2 = W1 + (64 + 4 * k4 + 2) * 32;
        const float* wb3 = W1 + (64 + 4 * k4 + 3) * 32;
        #pragma unroll
        for (int j = 0; j < 32; ++j) {
            float acc = h[j];
            acc = fmaf(a.x, wa0[j], acc);
            acc = fmaf(a.y, wa1[j], acc);
            acc = fmaf(a.z, wa2[j], acc);
            acc = fmaf(a.w, wa3[j], acc);
            acc = fmaf(b.x, wb0[j], acc);
            acc = fmaf(b.y, wb1[j], acc);
            acc = fmaf(b.z, wb2[j], acc);
            acc = fmaf(b.w, wb3[j], acc);
            h[j] = acc;
        }
    }

    float acc = b2[0];
    #pragma unroll
    for (int j = 0; j < 32; ++j) {
        float hv = h[j];
        hv = (hv >= 0.0f) ? hv : LEAKY * hv;
        acc = fmaf(hv, W2[j], acc);
    }
    out[e] = tanhf(acc);
}

extern "C" void kernel_launch(void* const* d_in, const int* in_sizes, int n_in,
                              void* d_out, int out_size, void* d_ws, size_t ws_size,
                              hipStream_t stream) {
    const float* z  = (const float*)d_in[0];
    const int*   idx = (const int*)d_in[1];
    const float* W1 = (const float*)d_in[2];
    const float* b1 = (const float*)d_in[3];
    const float* W2 = (const float*)d_in[4];
    const float* b2 = (const float*)d_in[5];
    float* out = (float*)d_out;

    const int E = out_size;            // 3,200,000
    const int N = in_sizes[0] / 64;    // 100,000 nodes

    size_t need = (size_t)2 * N * 32 * sizeof(__half);  // 12.8 MB
    if (ws_size >= need) {
        __half* U = (__half*)d_ws;
        __half* V = U + (size_t)N * 32;
        const int threads = 256;
        int nblocks_np = (N + 63) / 64;
        node_proj_v3<<<nblocks_np, threads, 0, stream>>>(z, W1, b1, U, V, N);
        edge_decode_q4<<<(E + threads - 1) / threads, threads, 0, stream>>>(
            idx, U, V, W2, b2, out, E);
    } else {
        const int threads = 256;
        edge_mlp_f32<<<(E + threads - 1) / threads, threads, 0, stream>>>(
            z, idx, W1, b1, W2, b2, out, E);
    }
}

// Round 11
// 176.137 us; speedup vs baseline: 1.0675x; 1.0675x over previous
//
#include <hip/hip_runtime.h>
#include <hip/hip_fp16.h>
#include <hip/hip_bf16.h>
#include <math.h>

#define LEAKY 0.01f

typedef __attribute__((ext_vector_type(8))) short short8v;
typedef __attribute__((ext_vector_type(4))) float f32x4;

__device__ inline float fast_tanh(float x) {
    float e2 = __expf(2.0f * x);
    return 1.0f - 2.0f * __builtin_amdgcn_rcpf(e2 + 1.0f);
}

__device__ inline float2 h2f(uint w) {
    __half2 h = *reinterpret_cast<__half2*>(&w);
    return __half22float2(h);
}

__device__ inline short f2bf(float f) {
    __hip_bfloat16 h = __float2bfloat16(f);
    short s;
    __builtin_memcpy(&s, &h, 2);
    return s;
}

// ---------------------------------------------------------------------------
// Kernel 1 (MFMA): [U||V] = z @ Wcat + bcat, Wcat = [W1_top ; W1_bot] (64x64),
// bcat = [b1 ; 0]. 256 rows/block, 4 waves x 64 rows. bf16 MFMA 16x16x32,
// fp32 accumulate, fp16 output rows for the edge gather.
//   A frag: lane l holds rows (l&15), k = kk*32 + (l>>4)*8 .. +7  (from global)
//   B frag: same k pattern, col = l&15 (from LDS, k-contiguous layout)
//   C/D  : col = l&15, row = (l>>4)*4 + reg   [verified m89/m91]
// ---------------------------------------------------------------------------
__global__ __launch_bounds__(256) void node_proj_mfma(
    const float* __restrict__ z, const float* __restrict__ W1,
    const float* __restrict__ b1, __half* __restrict__ U, __half* __restrict__ V,
    int N)
{
    __shared__ short w1l[64 * 72];        // Wcat bf16, [col][k] stride 72 (9.2 KB)
    __shared__ __half st[4][64 * 88];     // per-wave C staging, stride 88 (45 KB)

    int tid = threadIdx.x;
    int w = tid >> 6;
    int l = tid & 63;

    // ---- stage Wcat as bf16, layout w1l[col*72 + k] (k contiguous for b128) ----
    for (int i = tid; i < 4096; i += 256) {
        int j = i >> 6;   // col 0..63
        int k = i & 63;   // k   0..63
        float wv = (j < 32) ? W1[k * 32 + j] : W1[(64 + k) * 32 + (j - 32)];
        w1l[j * 72 + k] = f2bf(wv);
    }
    __syncthreads();

    // ---- A fragments straight from global (guarded), cvt f32->bf16 ----
    const float4* z4 = reinterpret_cast<const float4*>(z);
    int rbase = blockIdx.x * 256 + w * 64 + (l & 15);
    int koff = (l >> 4) * 8;
    short8v afr[4][2];
    #pragma unroll
    for (int mi = 0; mi < 4; ++mi) {
        int rg = rbase + mi * 16;
        bool ok = rg < N;
        size_t rowoff = (size_t)(ok ? rg : 0) * 16;
        #pragma unroll
        for (int kk = 0; kk < 2; ++kk) {
            int kq = (kk * 32 + koff) >> 2;
            float4 p0 = z4[rowoff + kq];
            float4 p1 = z4[rowoff + kq + 1];
            if (!ok) { p0 = make_float4(0, 0, 0, 0); p1 = make_float4(0, 0, 0, 0); }
            short8v f;
            f[0] = f2bf(p0.x); f[1] = f2bf(p0.y); f[2] = f2bf(p0.z); f[3] = f2bf(p0.w);
            f[4] = f2bf(p1.x); f[5] = f2bf(p1.y); f[6] = f2bf(p1.z); f[7] = f2bf(p1.w);
            afr[mi][kk] = f;
        }
    }

    // ---- MFMA: acc[mi][ni] over K=64 (2 steps of 32) ----
    f32x4 acc[4][4];
    #pragma unroll
    for (int mi = 0; mi < 4; ++mi)
        #pragma unroll
        for (int ni = 0; ni < 4; ++ni)
            acc[mi][ni] = (f32x4){0.0f, 0.0f, 0.0f, 0.0f};

    #pragma unroll
    for (int kk = 0; kk < 2; ++kk) {
        short8v bfr[4];
        #pragma unroll
        for (int ni = 0; ni < 4; ++ni) {
            int col = ni * 16 + (l & 15);
            bfr[ni] = *reinterpret_cast<const short8v*>(&w1l[col * 72 + kk * 32 + koff]);
        }
        #pragma unroll
        for (int mi = 0; mi < 4; ++mi)
            #pragma unroll
            for (int ni = 0; ni < 4; ++ni)
                acc[mi][ni] = __builtin_amdgcn_mfma_f32_16x16x32_bf16(
                    afr[mi][kk], bfr[ni], acc[mi][ni], 0, 0, 0);
    }

    // ---- bias + fp16 pack into per-wave LDS staging ----
    float bc[4];
    #pragma unroll
    for (int ni = 0; ni < 4; ++ni) {
        int col = ni * 16 + (l & 15);
        bc[ni] = (col < 32) ? b1[col] : 0.0f;
    }
    __half* stw = &st[w][0];
    #pragma unroll
    for (int mi = 0; mi < 4; ++mi)
        #pragma unroll
        for (int ni = 0; ni < 4; ++ni)
            #pragma unroll
            for (int r = 0; r < 4; ++r) {
                int row = mi * 16 + (l >> 4) * 4 + r;
                int col = ni * 16 + (l & 15);
                stw[row * 88 + col] = __float2half(acc[mi][ni][r] + bc[ni]);
            }
    __syncthreads();

    // ---- coalesced readback: each wave stores its own 64 rows ----
    int nb = blockIdx.x * 256 + w * 64;
    #pragma unroll
    for (int i = 0; i < 8; ++i) {
        int rl = i * 8 + (l >> 3);
        int c = l & 7;
        int n = nb + rl;
        if (n < N) {
            uint4 val = *reinterpret_cast<const uint4*>(&stw[rl * 88 + c * 8]);
            if (c < 4)
                *reinterpret_cast<uint4*>(U + (size_t)n * 32 + c * 8) = val;
            else
                *reinterpret_cast<uint4*>(V + (size_t)n * 32 + (c - 4) * 8) = val;
        }
    }
}

// ---------------------------------------------------------------------------
// Kernel 2: quad-cooperative edge decode, 4 edges per quad (unchanged; at the
// random-gather byte floor: ~293 MB L2-miss traffic @ ~3.8 TB/s).
// ---------------------------------------------------------------------------
__device__ inline float edge_dot(uint4 uq, uint4 vq, float4 w2a, float4 w2b) {
    float acc = 0.0f;
    float2 uu, vv; float h0, h1;
    uu = h2f(uq.x); vv = h2f(vq.x);
    h0 = uu.x + vv.x; h1 = uu.y + vv.y;
    h0 = (h0 >= 0.0f) ? h0 : LEAKY * h0;
    h1 = (h1 >= 0.0f) ? h1 : LEAKY * h1;
    acc = fmaf(h0, w2a.x, acc); acc = fmaf(h1, w2a.y, acc);
    uu = h2f(uq.y); vv = h2f(vq.y);
    h0 = uu.x + vv.x; h1 = uu.y + vv.y;
    h0 = (h0 >= 0.0f) ? h0 : LEAKY * h0;
    h1 = (h1 >= 0.0f) ? h1 : LEAKY * h1;
    acc = fmaf(h0, w2a.z, acc); acc = fmaf(h1, w2a.w, acc);
    uu = h2f(uq.z); vv = h2f(vq.z);
    h0 = uu.x + vv.x; h1 = uu.y + vv.y;
    h0 = (h0 >= 0.0f) ? h0 : LEAKY * h0;
    h1 = (h1 >= 0.0f) ? h1 : LEAKY * h1;
    acc = fmaf(h0, w2b.x, acc); acc = fmaf(h1, w2b.y, acc);
    uu = h2f(uq.w); vv = h2f(vq.w);
    h0 = uu.x + vv.x; h1 = uu.y + vv.y;
    h0 = (h0 >= 0.0f) ? h0 : LEAKY * h0;
    h1 = (h1 >= 0.0f) ? h1 : LEAKY * h1;
    acc = fmaf(h0, w2b.z, acc); acc = fmaf(h1, w2b.w, acc);
    return acc;
}

__global__ __launch_bounds__(256) void edge_decode_q4(
    const int* __restrict__ idx,
    const __half* __restrict__ U, const __half* __restrict__ V,
    const float* __restrict__ W2, const float* __restrict__ b2,
    float* __restrict__ out, int E)
{
    int t = blockIdx.x * blockDim.x + threadIdx.x;
    int p = t & 3;
    int e0 = t & ~3;
    if (e0 >= E) return;
    int eN = E - 1;
    int ea = min(e0, eN), eb = min(e0 + 1, eN), ec = min(e0 + 2, eN), ed = min(e0 + 3, eN);

    int s0 = idx[ea], s1 = idx[eb], s2 = idx[ec], s3 = idx[ed];
    int d0 = idx[E + ea], d1 = idx[E + eb], d2 = idx[E + ec], d3 = idx[E + ed];

    const uint4* Up = reinterpret_cast<const uint4*>(U);
    const uint4* Vp = reinterpret_cast<const uint4*>(V);
    uint4 u0 = Up[(size_t)s0 * 4 + p];
    uint4 u1 = Up[(size_t)s1 * 4 + p];
    uint4 u2 = Up[(size_t)s2 * 4 + p];
    uint4 u3 = Up[(size_t)s3 * 4 + p];
    uint4 v0 = Vp[(size_t)d0 * 4 + p];
    uint4 v1 = Vp[(size_t)d1 * 4 + p];
    uint4 v2 = Vp[(size_t)d2 * 4 + p];
    uint4 v3 = Vp[(size_t)d3 * 4 + p];

    float4 w2a = *reinterpret_cast<const float4*>(W2 + p * 8);
    float4 w2b = *reinterpret_cast<const float4*>(W2 + p * 8 + 4);

    float a0 = edge_dot(u0, v0, w2a, w2b);
    float a1 = edge_dot(u1, v1, w2a, w2b);
    float a2 = edge_dot(u2, v2, w2a, w2b);
    float a3 = edge_dot(u3, v3, w2a, w2b);

    a0 += __shfl_xor(a0, 1); a0 += __shfl_xor(a0, 2);
    a1 += __shfl_xor(a1, 1); a1 += __shfl_xor(a1, 2);
    a2 += __shfl_xor(a2, 1); a2 += __shfl_xor(a2, 2);
    a3 += __shfl_xor(a3, 1); a3 += __shfl_xor(a3, 2);

    float r = (p == 0) ? a0 : (p == 1) ? a1 : (p == 2) ? a2 : a3;
    r = fast_tanh(r + b2[0]);
    int eo = e0 + p;
    if (eo < E) out[eo] = r;
}

// ---------------------------------------------------------------------------
// Fallback if the workspace is too small for U/V.
// ---------------------------------------------------------------------------
__global__ __launch_bounds__(256) void edge_mlp_f32(
    const float* __restrict__ z, const int* __restrict__ idx,
    const float* __restrict__ W1, const float* __restrict__ b1,
    const float* __restrict__ W2, const float* __restrict__ b2,
    float* __restrict__ out, int E)
{
    int e = blockIdx.x * blockDim.x + threadIdx.x;
    if (e >= E) return;
    int s = idx[e];
    int d = idx[E + e];
    const float4* zs = reinterpret_cast<const float4*>(z + (size_t)s * 64);
    const float4* zd = reinterpret_cast<const float4*>(z + (size_t)d * 64);

    float h[32];
    #pragma unroll
    for (int j = 0; j < 32; ++j) h[j] = b1[j];

    #pragma unroll 4
    for (int k4 = 0; k4 < 16; ++k4) {
        float4 a = zs[k4];
        float4 b = zd[k4];
        const float* wa0 = W1 + (4 * k4 + 0) * 32;
        const float* wa1 = W1 + (4 * k4 + 1) * 32;
        const float* wa2 = W1 + (4 * k4 + 2) * 32;
        const float* wa3 = W1 + (4 * k4 + 3) * 32;
        const float* wb0 = W1 + (64 + 4 * k4 + 0) * 32;
        const float* wb1 = W1 + (64 + 4 * k4 + 1) * 32;
        const float* wb2 = W1 + (64 + 4 * k4 + 2) * 32;
        const float* wb3 = W1 + (64 + 4 * k4 + 3) * 32;
        #pragma unroll
        for (int j = 0; j < 32; ++j) {
            float acc = h[j];
            acc = fmaf(a.x, wa0[j], acc);
            acc = fmaf(a.y, wa1[j], acc);
            acc = fmaf(a.z, wa2[j], acc);
            acc = fmaf(a.w, wa3[j], acc);
            acc = fmaf(b.x, wb0[j], acc);
            acc = fmaf(b.y, wb1[j], acc);
            acc = fmaf(b.z, wb2[j], acc);
            acc = fmaf(b.w, wb3[j], acc);
            h[j] = acc;
        }
    }

    float acc = b2[0];
    #pragma unroll
    for (int j = 0; j < 32; ++j) {
        float hv = h[j];
        hv = (hv >= 0.0f) ? hv : LEAKY * hv;
        acc = fmaf(hv, W2[j], acc);
    }
    out[e] = tanhf(acc);
}

extern "C" void kernel_launch(void* const* d_in, const int* in_sizes, int n_in,
                              void* d_out, int out_size, void* d_ws, size_t ws_size,
                              hipStream_t stream) {
    const float* z  = (const float*)d_in[0];
    const int*   idx = (const int*)d_in[1];
    const float* W1 = (const float*)d_in[2];
    const float* b1 = (const float*)d_in[3];
    const float* W2 = (const float*)d_in[4];
    const float* b2 = (const float*)d_in[5];
    float* out = (float*)d_out;

    const int E = out_size;            // 3,200,000
    const int N = in_sizes[0] / 64;    // 100,000 nodes

    size_t need = (size_t)2 * N * 32 * sizeof(__half);  // 12.8 MB
    if (ws_size >= need) {
        __half* U = (__half*)d_ws;
        __half* V = U + (size_t)N * 32;
        const int threads = 256;
        int nblocks_np = (N + 255) / 256;
        node_proj_mfma<<<nblocks_np, threads, 0, stream>>>(z, W1, b1, U, V, N);
        edge_decode_q4<<<(E + threads - 1) / threads, threads, 0, stream>>>(
            idx, U, V, W2, b2, out, E);
    } else {
        const int threads = 256;
        edge_mlp_f32<<<(E + threads - 1) / threads, threads, 0, stream>>>(
            z, idx, W1, b1, W2, b2, out, E);
    }
}